// Round 1
// baseline (429.025 us; speedup 1.0000x reference)
//
#include <hip/hip_runtime.h>
#include <math.h>

namespace {
constexpr int   kB      = 256;
constexpr int   kD      = 128;
constexpr int   kC      = 100000;
constexpr float kScale  = 35.0f;
constexpr float kCosM   = 0.87758256189037276f;   // cos(0.5)
constexpr float kSinM   = 0.47942553860420301f;   // sin(0.5)
constexpr float kThresh = -0.87758256189037276f;  // -cos(0.5)
constexpr float kExt    = -0.5f * 0.47942553860420301f; // -m*sin(m)
}

// ---------------- norms: rn[0..C-1] = rsqrt(||w_c||^2), rn[C..C+B-1] = rsqrt(||f_b||^2)
__global__ __launch_bounds__(256)
void arcface_norms(const float* __restrict__ feat,
                   const float* __restrict__ wgt,
                   float* __restrict__ rn) {
    const int wid  = (blockIdx.x * 256 + threadIdx.x) >> 6;  // one wave per row
    const int lane = threadIdx.x & 63;
    if (wid >= kC + kB) return;
    const float* row = (wid < kC) ? (wgt + (size_t)wid * kD)
                                  : (feat + (size_t)(wid - kC) * kD);
    const float2 v = *(const float2*)(row + (lane << 1));
    float s = v.x * v.x + v.y * v.y;
    #pragma unroll
    for (int off = 32; off > 0; off >>= 1) s += __shfl_down(s, off, 64);
    if (lane == 0) rn[wid] = rsqrtf(s);
}

// ---------------- main GEMM: 128x128 tile, K chunked x64, 8x8 per thread
__global__ __launch_bounds__(256)
void arcface_main(const float* __restrict__ feat,
                  const float* __restrict__ wgt,
                  const float* __restrict__ rn,
                  float* __restrict__ out_cos,
                  float* __restrict__ out_marg,
                  float* __restrict__ out_ip) {
    // k-major tiles: element (k, r) stored at k*128 + ((g ^ kq)<<2) + (r&3),
    // g = r>>2 (0..31), kq = k>>2 (0..15).  XOR swizzle -> conflict-free
    // ds_write_b128 staging AND ds_read_b128 fragments.
    __shared__ float sA[64 * 128];
    __shared__ float sB[64 * 128];

    const int t  = threadIdx.x;
    const int tx = t & 15;
    const int ty = t >> 4;
    const int b0 = blockIdx.x * 128;   // 2 b-tiles (fastest -> weight L2 reuse)
    const int c0 = blockIdx.y * 128;   // 782 c-tiles

    float acc[8][8];
    #pragma unroll
    for (int i = 0; i < 8; ++i)
        #pragma unroll
        for (int j = 0; j < 8; ++j) acc[i][j] = 0.f;

    for (int ch = 0; ch < 2; ++ch) {
        const int k0 = ch * 64;
        // ---- stage: each thread loads 4 micro-tiles (4 rows x float4-of-k),
        // transposes in-register, writes 4x ds_write_b128 along r.
        #pragma unroll
        for (int m = 0; m < 4; ++m) {
            const int mt    = t + (m << 8);
            const int kq    = mt & 15;
            const int rgAll = mt >> 4;          // 0..31 -> sA, 32..63 -> sB
            const int g     = rgAll & 31;
            const int r     = g << 2;
            float4 v[4];
            if (rgAll < 32) {
                const float* src = feat + (size_t)(b0 + r) * kD + k0 + (kq << 2);
                #pragma unroll
                for (int j = 0; j < 4; ++j) v[j] = *(const float4*)(src + j * kD);
            } else {
                #pragma unroll
                for (int j = 0; j < 4; ++j) {
                    const int row = c0 + r + j;
                    v[j] = (row < kC)
                         ? *(const float4*)(wgt + (size_t)row * kD + k0 + (kq << 2))
                         : make_float4(0.f, 0.f, 0.f, 0.f);
                }
            }
            float* dst = (rgAll < 32) ? sA : sB;
            const float* vf = (const float*)v;
            const int pos = (g ^ kq) << 2;
            #pragma unroll
            for (int i2 = 0; i2 < 4; ++i2) {
                *(float4*)(dst + ((kq << 2) + i2) * 128 + pos) =
                    make_float4(vf[i2], vf[4 + i2], vf[8 + i2], vf[12 + i2]);
            }
        }
        __syncthreads();

        #pragma unroll 4
        for (int k = 0; k < 64; ++k) {
            const int kq = (k >> 2) & 15;
            const float4 a0 = *(const float4*)(sA + k * 128 + ((ty ^ kq) << 2));
            const float4 a1 = *(const float4*)(sA + k * 128 + ((16 + (ty ^ kq)) << 2));
            const float4 w0 = *(const float4*)(sB + k * 128 + ((tx ^ kq) << 2));
            const float4 w1 = *(const float4*)(sB + k * 128 + ((16 + (tx ^ kq)) << 2));
            const float av[8] = {a0.x, a0.y, a0.z, a0.w, a1.x, a1.y, a1.z, a1.w};
            const float bv[8] = {w0.x, w0.y, w0.z, w0.w, w1.x, w1.y, w1.z, w1.w};
            #pragma unroll
            for (int i = 0; i < 8; ++i)
                #pragma unroll
                for (int j = 0; j < 8; ++j)
                    acc[i][j] = fmaf(av[i], bv[j], acc[i][j]);
        }
        __syncthreads();
    }

    // ---- epilogue: cos = ip * rf * rw; marg = 35*cos; ip as-is.
    float rf[8], rw[8];
    #pragma unroll
    for (int i = 0; i < 8; ++i) {
        const int ri = (i < 4) ? ((ty << 2) + i) : (64 + (ty << 2) + i - 4);
        rf[i] = rn[kC + b0 + ri];
    }
    #pragma unroll
    for (int j = 0; j < 8; ++j) {
        const int cj = (j < 4) ? ((tx << 2) + j) : (64 + (tx << 2) + j - 4);
        rw[j] = rn[c0 + cj];   // c0+cj <= 100095 < 100256: in-bounds even off-edge
    }
    #pragma unroll
    for (int i = 0; i < 8; ++i) {
        const int bIdx = b0 + ((i < 4) ? ((ty << 2) + i) : (64 + (ty << 2) + i - 4));
        float* pc = out_cos  + (size_t)bIdx * kC;
        float* pm = out_marg + (size_t)bIdx * kC;
        float* pi = out_ip   + (size_t)bIdx * kC;
        #pragma unroll
        for (int h = 0; h < 2; ++h) {
            const int c = c0 + h * 64 + (tx << 2);
            if (c < kC) {
                const float i0 = acc[i][h * 4 + 0], i1 = acc[i][h * 4 + 1];
                const float i2 = acc[i][h * 4 + 2], i3 = acc[i][h * 4 + 3];
                const float c0v = i0 * rf[i] * rw[h * 4 + 0];
                const float c1v = i1 * rf[i] * rw[h * 4 + 1];
                const float c2v = i2 * rf[i] * rw[h * 4 + 2];
                const float c3v = i3 * rf[i] * rw[h * 4 + 3];
                *(float4*)(pi + c) = make_float4(i0, i1, i2, i3);
                *(float4*)(pc + c) = make_float4(c0v, c1v, c2v, c3v);
                *(float4*)(pm + c) = make_float4(kScale * c0v, kScale * c1v,
                                                 kScale * c2v, kScale * c3v);
            }
        }
    }
}

// ---------------- gt-column fixup on marginal logits
__global__ void arcface_fixup(const int* __restrict__ label,
                              const float* __restrict__ out_cos,
                              float* __restrict__ out_marg) {
    const int b = threadIdx.x;
    // hedge: detect int64-layout labels (odd int32 slots all zero)
    bool is64 = true;
    #pragma unroll
    for (int i = 1; i < 24; i += 2) is64 = is64 && (label[i] == 0);
    const int c = is64 ? label[2 * b] : label[b];
    const size_t idx = (size_t)b * kC + c;
    const float cosv = out_cos[idx];
    const float cc = fminf(1.f, fmaxf(-1.f, cosv));
    float marg;
    if (cosv > kThresh) {
        marg = cc * kCosM - sqrtf(fmaxf(0.f, 1.f - cc * cc)) * kSinM;
    } else {
        marg = cc + kExt;
    }
    out_marg[idx] = kScale * marg;
}

extern "C" void kernel_launch(void* const* d_in, const int* in_sizes, int n_in,
                              void* d_out, int out_size, void* d_ws, size_t ws_size,
                              hipStream_t stream) {
    const float* feat  = (const float*)d_in[0];
    const float* wgt   = (const float*)d_in[1];
    const int*   label = (const int*)d_in[2];
    float* out_cos  = (float*)d_out;
    float* out_marg = out_cos  + (size_t)kB * kC;
    float* out_ip   = out_marg + (size_t)kB * kC;
    float* rn = (float*)d_ws;   // (kC + kB) floats of scratch

    arcface_norms<<<(kC + kB + 3) / 4, 256, 0, stream>>>(feat, wgt, rn);
    dim3 grid(2, (kC + 127) / 128);
    arcface_main<<<grid, 256, 0, stream>>>(feat, wgt, rn, out_cos, out_marg, out_ip);
    arcface_fixup<<<1, 256, 0, stream>>>(label, out_cos, out_marg);
}

// Round 2
// 369.693 us; speedup vs baseline: 1.1605x; 1.1605x over previous
//
#include <hip/hip_runtime.h>
#include <math.h>

using short8  = __attribute__((ext_vector_type(8))) short;
using floatx4 = __attribute__((ext_vector_type(4))) float;

namespace {
constexpr int   kB      = 256;
constexpr int   kD      = 128;
constexpr int   kC      = 100000;
constexpr float kScale  = 35.0f;
constexpr float kCosM   = 0.87758256189037276f;   // cos(0.5)
constexpr float kSinM   = 0.47942553860420301f;   // sin(0.5)
constexpr float kThresh = -0.87758256189037276f;  // -cos(0.5)
constexpr float kExt    = -0.5f * 0.47942553860420301f; // -m*sin(m)

// ws layout (bytes), all 16B-aligned:
constexpr size_t kWgtBfOff  = 0;                                  // 100000 rows x 256B (swizzled)
constexpr size_t kFeatBfOff = (size_t)kC * 256;                   // 25,600,000: 256 rows x 256B (plain)
constexpr size_t kRwOff     = kFeatBfOff + (size_t)kB * 256;      // 25,665,536: 100000 f32
constexpr size_t kRfOff     = kRwOff + (size_t)kC * 4;            // 26,065,536: 256 f32
}

__device__ inline unsigned short f2bf(float f) {
    unsigned u = __builtin_bit_cast(unsigned, f);
    return (unsigned short)((u + 0x7fffu + ((u >> 16) & 1u)) >> 16);  // RNE
}

__device__ inline void async16(void* lds, const void* g) {
    __builtin_amdgcn_global_load_lds(
        (const __attribute__((address_space(1))) void*)g,
        (__attribute__((address_space(3))) void*)lds, 16, 0, 0);
}

// ---------------- prep: norms + fp32->bf16 conversion (weights swizzled)
__global__ __launch_bounds__(256)
void arcface_prep(const float* __restrict__ feat,
                  const float* __restrict__ wgt,
                  unsigned char* __restrict__ ws) {
    const int wid = blockIdx.x * 4 + (threadIdx.x >> 6);   // one wave per row
    const int l   = threadIdx.x & 63;
    if (wid >= kC + kB) return;
    const bool isW = wid < kC;
    const float* src = isW ? (wgt + (size_t)wid * kD)
                           : (feat + (size_t)(wid - kC) * kD);
    const float2 v = *(const float2*)(src + 2 * l);
    float s = v.x * v.x + v.y * v.y;
    #pragma unroll
    for (int off = 32; off > 0; off >>= 1) s += __shfl_down(s, off, 64);

    const unsigned packed = (unsigned)f2bf(v.x) | ((unsigned)f2bf(v.y) << 16);
    if (isW) {
        unsigned* row = (unsigned*)(ws + kWgtBfOff + (size_t)wid * 256);
        row[(l + (wid & 15) * 4) & 63] = packed;           // 16B-block rotation by (c&15)
        if (l == 0) *(float*)(ws + kRwOff + (size_t)wid * 4) = rsqrtf(s);
    } else {
        unsigned* row = (unsigned*)(ws + kFeatBfOff + (size_t)(wid - kC) * 256);
        row[l] = packed;
        if (l == 0) *(float*)(ws + kRfOff + (size_t)(wid - kC) * 4) = rsqrtf(s);
    }
}

// ---------------- main MFMA GEMM: M=256 x N=64 per tile, 2 tiles per block
__global__ __launch_bounds__(256, 2)
void arcface_gemm(const unsigned char* __restrict__ ws,
                  float* __restrict__ out_cos,
                  float* __restrict__ out_marg,
                  float* __restrict__ out_ip) {
    __shared__ short sB[2][64 * 128];        // 2 x 16 KB, verbatim copies of bf16 weight rows
    __shared__ float sScr[4][16 * 68];       // per-wave transpose scratch (stride 68 -> 16B-aligned b128)

    const int t   = threadIdx.x;
    const int l   = t & 63;
    const int w   = t >> 6;
    const int q   = l >> 4;      // quad 0..3
    const int c16 = l & 15;
    const int m0  = w * 64;

    const short* featbf = (const short*)(ws + kFeatBfOff);
    const short* wgtbf  = (const short*)(ws + kWgtBfOff);
    const float* rw_g   = (const float*)(ws + kRwOff);
    const float* rf_g   = (const float*)(ws + kRfOff);

    const int tile0 = blockIdx.x * 2;        // grid 782 -> tiles 0..1563 (1563 fully masked)

    // stage both B tiles async (16 KB each: 4 passes x 256 thr x 16B)
    #pragma unroll
    for (int it = 0; it < 2; ++it) {
        const char* src = (const char*)wgtbf + (size_t)(tile0 + it) * 16384;
        char* dst = (char*)&sB[it][0];
        #pragma unroll
        for (int p = 0; p < 4; ++p)
            async16(dst + p * 4096 + t * 16, src + p * 4096 + t * 16);
    }

    // A fragments resident: wave's 64 m-rows x K=128 (A: m=lane&15, k=quad*8+j)
    short8 aF[4][4];
    #pragma unroll
    for (int mi = 0; mi < 4; ++mi)
        #pragma unroll
        for (int kq = 0; kq < 4; ++kq)
            aF[mi][kq] = *(const short8*)(featbf + (size_t)(m0 + mi * 16 + c16) * kD + kq * 32 + q * 8);

    __syncthreads();   // drains vmcnt(0): both B tiles + aF ready

    #pragma unroll
    for (int it = 0; it < 2; ++it) {
        const short* bbuf = &sB[it][0];
        floatx4 acc[4][4];
        #pragma unroll
        for (int mi = 0; mi < 4; ++mi)
            #pragma unroll
            for (int nt = 0; nt < 4; ++nt)
                acc[mi][nt] = (floatx4){0.f, 0.f, 0.f, 0.f};

        #pragma unroll
        for (int kq = 0; kq < 4; ++kq) {
            short8 bF[4];
            const int s = (q + c16 + kq * 4) & 15;   // undo per-row rotation
            #pragma unroll
            for (int nt = 0; nt < 4; ++nt)
                bF[nt] = *(const short8*)(bbuf + (nt * 16 + c16) * 128 + s * 8);
            #pragma unroll
            for (int mi = 0; mi < 4; ++mi)
                #pragma unroll
                for (int nt = 0; nt < 4; ++nt)
                    acc[mi][nt] = __builtin_amdgcn_mfma_f32_16x16x32_bf16(
                        aF[mi][kq], bF[nt], acc[mi][nt], 0, 0, 0);
        }

        // epilogue: per-wave LDS transpose -> coalesced float4 stores
        const int c0n = (tile0 + it) * 64;
        float* scr = &sScr[w][0];
        #pragma unroll
        for (int mi = 0; mi < 4; ++mi) {
            #pragma unroll
            for (int nt = 0; nt < 4; ++nt)
                #pragma unroll
                for (int r = 0; r < 4; ++r)
                    scr[(q * 4 + r) * 68 + nt * 16 + c16] = acc[mi][nt][r];
            // compiler inserts lgkmcnt wait for same-LDS dependence
            #pragma unroll
            for (int jj = 0; jj < 4; ++jj) {
                const int rr = q + 4 * jj;
                const floatx4 ip = *(const floatx4*)(scr + rr * 68 + c16 * 4);
                const int m = m0 + mi * 16 + rr;
                const int c = c0n + c16 * 4;
                if (c < kC) {
                    const float rf = rf_g[m];
                    const floatx4 rw4 = *(const floatx4*)(rw_g + c);
                    const floatx4 cs = ip * rf * rw4;
                    const size_t o = (size_t)m * kC + c;
                    *(floatx4*)(out_ip + o)   = ip;
                    *(floatx4*)(out_cos + o)  = cs;
                    *(floatx4*)(out_marg + o) = cs * kScale;
                }
            }
        }
    }
}

// ---------------- gt-column fixup on marginal logits
__global__ void arcface_fixup(const int* __restrict__ label,
                              const float* __restrict__ out_cos,
                              float* __restrict__ out_marg) {
    const int b = threadIdx.x;
    bool is64 = true;
    #pragma unroll
    for (int i = 1; i < 24; i += 2) is64 = is64 && (label[i] == 0);
    const int c = is64 ? label[2 * b] : label[b];
    const size_t idx = (size_t)b * kC + c;
    const float cosv = out_cos[idx];
    const float cc = fminf(1.f, fmaxf(-1.f, cosv));
    float marg;
    if (cosv > kThresh) {
        marg = cc * kCosM - sqrtf(fmaxf(0.f, 1.f - cc * cc)) * kSinM;
    } else {
        marg = cc + kExt;
    }
    out_marg[idx] = kScale * marg;
}

extern "C" void kernel_launch(void* const* d_in, const int* in_sizes, int n_in,
                              void* d_out, int out_size, void* d_ws, size_t ws_size,
                              hipStream_t stream) {
    const float* feat  = (const float*)d_in[0];
    const float* wgt   = (const float*)d_in[1];
    const int*   label = (const int*)d_in[2];
    float* out_cos  = (float*)d_out;
    float* out_marg = out_cos  + (size_t)kB * kC;
    float* out_ip   = out_marg + (size_t)kB * kC;
    unsigned char* ws = (unsigned char*)d_ws;

    arcface_prep<<<(kC + kB + 3) / 4, 256, 0, stream>>>(feat, wgt, ws);
    arcface_gemm<<<782, 256, 0, stream>>>(ws, out_cos, out_marg, out_ip);
    arcface_fixup<<<1, 256, 0, stream>>>(label, out_cos, out_marg);
}